// Round 7
// baseline (436.850 us; speedup 1.0000x reference)
//
#include <hip/hip_runtime.h>
#include <cstdint>
#include <cstddef>

#define NB 16
#define NC 84
#define NA 33600
#define NCLS 80
#define TOPK 1024
#define NBIN 8192        // coarse bins: mono_u32 >> 19
#define CANDCAP 8192
#define SCORE_THR 0.005f
#define IOU_THR 0.5f

// ---- 64-bit sort key: (monotonic fp32) << 32 | ~index ----------------------
// Larger key == (higher score, then lower index) == jax.lax.top_k order.
__device__ __forceinline__ unsigned mono_u32(float f) {
    unsigned u = __float_as_uint(f);
    return (u & 0x80000000u) ? ~u : (u | 0x80000000u);
}
__device__ __forceinline__ float key_val(uint64_t k) {
    unsigned u = (unsigned)(k >> 32);
    u = (u & 0x80000000u) ? (u & 0x7FFFFFFFu) : ~u;
    return __uint_as_float(u);
}
__device__ __forceinline__ int key_idx(uint64_t k) {
    return (int)(~(uint32_t)(k & 0xFFFFFFFFu));
}

// ---- K1: max/argmax over 80 classes (float4) + LDS-private histogram -------
// grid (33, NB): block handles 1024 anchors (256 float4) of one batch.
__global__ __launch_bounds__(256) void score_hist_kernel(const float* __restrict__ x,
                                                         float* __restrict__ sval,
                                                         int* __restrict__ cid,
                                                         unsigned* __restrict__ hist) {
    __shared__ unsigned h[NBIN];
    const int t = threadIdx.x;
    const int b = blockIdx.y;
    for (int i = t; i < NBIN; i += 256) h[i] = 0;
    __syncthreads();
    int q = blockIdx.x * 256 + t;                 // float4 index within batch
    if (q < NA / 4) {
        const float4* p = (const float4*)(x + (size_t)b * NC * NA + (size_t)4 * NA) + q;
        float4 best = p[0];
        int4 bc = {0, 0, 0, 0};
#pragma unroll 8
        for (int c = 1; c < NCLS; ++c) {
            float4 v = p[(size_t)c * (NA / 4)];
            if (v.x > best.x) { best.x = v.x; bc.x = c; }
            if (v.y > best.y) { best.y = v.y; bc.y = c; }
            if (v.z > best.z) { best.z = v.z; bc.z = c; }
            if (v.w > best.w) { best.w = v.w; bc.w = c; }
        }
        float4 s;
        s.x = (best.x > SCORE_THR) ? best.x : -INFINITY;
        s.y = (best.y > SCORE_THR) ? best.y : -INFINITY;
        s.z = (best.z > SCORE_THR) ? best.z : -INFINITY;
        s.w = (best.w > SCORE_THR) ? best.w : -INFINITY;
        ((float4*)sval)[(size_t)b * (NA / 4) + q] = s;
        ((int4*)cid)[(size_t)b * (NA / 4) + q] = bc;
        atomicAdd(&h[mono_u32(s.x) >> 19], 1u);
        atomicAdd(&h[mono_u32(s.y) >> 19], 1u);
        atomicAdd(&h[mono_u32(s.z) >> 19], 1u);
        atomicAdd(&h[mono_u32(s.w) >> 19], 1u);
    }
    __syncthreads();
    unsigned* gh = hist + (size_t)b * NBIN;
    for (int i = t; i < NBIN; i += 256) {
        unsigned v = h[i];
        if (v) atomicAdd(&gh[i], v);
    }
}

// ---- K2: per-block cutbin recompute + compact slice ------------------------
// grid (16, NB): each block scans the (L2-hot) hist, then compacts 2100 anchors.
__global__ __launch_bounds__(256) void select_kernel(const float* __restrict__ sval,
                                                     const unsigned* __restrict__ hist,
                                                     uint64_t* __restrict__ cand,
                                                     unsigned* __restrict__ cnt) {
    __shared__ unsigned csum[256];
    __shared__ unsigned scut, lc, lbase;
    __shared__ uint64_t cbuf[2112];
    const int t = threadIdx.x;
    const int b = blockIdx.y;
    const int sl = blockIdx.x;

    const unsigned* gh = hist + (size_t)b * NBIN;
    unsigned cnts[32];
    unsigned local = 0;
#pragma unroll
    for (int q = 0; q < 32; ++q) {
        cnts[q] = gh[NBIN - 1 - (t * 32 + q)];
        local += cnts[q];
    }
    csum[t] = local;
    __syncthreads();
    for (int off = 1; off < 256; off <<= 1) {
        unsigned v = (t >= off) ? csum[t - off] : 0u;
        __syncthreads();
        csum[t] += v;
        __syncthreads();
    }
    unsigned incl = csum[t], excl = incl - local;
    if (excl < TOPK && incl >= TOPK) {
        unsigned cum = excl;
#pragma unroll
        for (int q = 0; q < 32; ++q) {
            if (cum + cnts[q] >= TOPK) { scut = (unsigned)(NBIN - 1 - (t * 32 + q)); break; }
            cum += cnts[q];
        }
    }
    if (t == 0) lc = 0;
    __syncthreads();
    unsigned cb = scut;

    int a0 = sl * (NA / 16);
    const float* sv = sval + (size_t)b * NA;
    for (int a = a0 + t; a < a0 + NA / 16; a += 256) {
        unsigned u = mono_u32(sv[a]);
        if ((u >> 19) >= cb) {
            unsigned pos = atomicAdd(&lc, 1u);
            cbuf[pos] = ((uint64_t)u << 32) | (uint32_t)(~(uint32_t)a);
        }
    }
    __syncthreads();
    if (t == 0) lbase = lc ? atomicAdd(&cnt[b * 64], lc) : 0u;
    __syncthreads();
    for (unsigned i = t; i < lc; i += 256) {
        unsigned p = lbase + i;
        if (p < CANDCAP) cand[((size_t)b << 13) + p] = cbuf[i];
    }
}

// ---- K3: exact top-1024 by rank-counting + fused box/cid gather ------------
// grid (4, NB). Keys unique -> ranks unique -> output bit-identical to top_k.
__global__ __launch_bounds__(256) void rank_gather_kernel(const float* __restrict__ x,
                                                          const int* __restrict__ cid,
                                                          const uint64_t* __restrict__ cand,
                                                          const unsigned* __restrict__ cnt,
                                                          float* __restrict__ tval,
                                                          float* __restrict__ bx1, float* __restrict__ by1,
                                                          float* __restrict__ bx2, float* __restrict__ by2,
                                                          float* __restrict__ barr, int* __restrict__ tcid) {
    __shared__ uint64_t lk[CANDCAP];   // 64 KB
    const int t = threadIdx.x;
    const int b = blockIdx.y;
    const int sl = blockIdx.x;
    unsigned C = cnt[b * 64];
    if (C > CANDCAP) C = CANDCAP;
    const uint64_t* cb = cand + ((size_t)b << 13);
    for (unsigned i = t; i < C; i += 256) lk[i] = cb[i];
    __syncthreads();

    const int base = b << 10;
    const float* xb = x + (size_t)b * NC * NA;
    for (int i0 = sl * 256 + t; i0 < (int)C; i0 += 1024) {
        uint64_t my = lk[i0];
        unsigned rank = 0;
        int j = 0;
        for (; j + 4 <= (int)C; j += 4) {
            rank += (lk[j] > my);
            rank += (lk[j + 1] > my);
            rank += (lk[j + 2] > my);
            rank += (lk[j + 3] > my);
        }
        for (; j < (int)C; ++j) rank += (lk[j] > my);
        if (rank < TOPK) {
            int idx = key_idx(my);
            tval[base + rank] = key_val(my);
            float x1 = xb[idx], y1 = xb[NA + idx], x2 = xb[2 * NA + idx], y2 = xb[3 * NA + idx];
            bx1[base + rank] = x1; by1[base + rank] = y1;
            bx2[base + rank] = x2; by2[base + rank] = y2;
            barr[base + rank] = (x2 - x1) * (y2 - y1);
            tcid[base + rank] = cid[b * NA + idx];
        }
    }
}

// ---- K4: suppression bit-matrix + last-block-fused serial sweep ------------
// grid (64, NB): block handles 16 rows. Last finishing block of each batch
// (device-scope done counter, fence/acquire) runs the greedy sweep + epilogue.
// Sweep chunks are staged in LDS (NOT a dynamically-indexed register array —
// that spills to scratch and costs ~500 cyc/row in the serial chain).
#define LDSPAD(j) ((j) + ((j) >> 6))
__global__ __launch_bounds__(256) void mask_sweep_kernel(const float* __restrict__ tval,
                                                         const int* __restrict__ tcid,
                                                         const float* __restrict__ bx1,
                                                         const float* __restrict__ by1,
                                                         const float* __restrict__ bx2,
                                                         const float* __restrict__ by2,
                                                         const float* __restrict__ barr,
                                                         uint64_t* __restrict__ M,
                                                         int* __restrict__ rowflag,
                                                         unsigned* __restrict__ done,
                                                         float* __restrict__ out) {
    // smem layout: [0,20800) box SoA (5 x 1040 floats)  — reused as lrows in sweep
    //              [20800,21824) anyf                   [21824,25920) list
    __shared__ __align__(16) char smem[25920];
    __shared__ unsigned sdone;
    float* sx1 = (float*)smem;
    float* sy1 = sx1 + (TOPK + 16);
    float* sx2 = sy1 + (TOPK + 16);
    float* sy2 = sx2 + (TOPK + 16);
    float* sar = sy2 + (TOPK + 16);
    int* anyf = (int*)(smem + 20800);
    int* list = (int*)(smem + 21824);

    const int t = threadIdx.x;
    const int b = blockIdx.y;
    const int base = b << 10;

    for (int j = t; j < TOPK; j += 256) {
        int ji = LDSPAD(j);
        sx1[ji] = bx1[base + j]; sy1[ji] = by1[base + j];
        sx2[ji] = bx2[base + j]; sy2[ji] = by2[base + j];
        sar[ji] = barr[base + j];
    }
    __syncthreads();

    int w = t & 15;
    int r = (blockIdx.x << 4) + (t >> 4);
    int ri = LDSPAD(r);
    float ix1 = sx1[ri], iy1 = sy1[ri], ix2 = sx2[ri], iy2 = sy2[ri], ia = sar[ri];
    uint64_t m = 0;
#pragma unroll 8
    for (int jj = 0; jj < 64; ++jj) {
        int j = (w << 6) + jj;
        int ji = w * 65 + jj;
        float ltx = fmaxf(ix1, sx1[ji]);
        float lty = fmaxf(iy1, sy1[ji]);
        float rbx = fminf(ix2, sx2[ji]);
        float rby = fminf(iy2, sy2[ji]);
        float ww = fmaxf(rbx - ltx, 0.0f);
        float hh = fmaxf(rby - lty, 0.0f);
        float inter = ww * hh;
        float uni = ia + sar[ji] - inter;      // same op order as reference
        float iou = inter / fmaxf(uni, 1e-9f);
        if (j > r && iou > IOU_THR) m |= (1ULL << jj);
    }
    M[(((size_t)(base + r)) << 4) + w] = m;
    anyf[t] = (m != 0ULL);
    __syncthreads();
    if (w == 0) {
        int any = 0;
#pragma unroll
        for (int q = 0; q < 16; ++q) any |= anyf[t + q];
        bool valid = tval[base + r] > SCORE_THR;
        rowflag[base + r] = (any && valid) ? 1 : 0;
    }

    // ---- publish, then elect last block ----
    __syncthreads();
    __threadfence();
    if (t == 0)
        sdone = __hip_atomic_fetch_add(&done[b], 1u, __ATOMIC_ACQ_REL, __HIP_MEMORY_SCOPE_AGENT);
    __syncthreads();
    if (sdone != 63) return;

    // ---- serial greedy sweep (wave 0 only; no __syncthreads below) ----
    if (t >= 64) return;
    int l = t;
    int gg = l >> 4;
    w = l & 15;
    uint64_t* lrows = (uint64_t*)smem;   // overlays dead box SoA; 64*16*8 = 8 KB

    float tv[16];
#pragma unroll
    for (int s = 0; s < 16; ++s) tv[s] = tval[base + (s << 6) + l];

    uint64_t vword = 0;
#pragma unroll
    for (int s = 0; s < 16; ++s) {
        uint64_t bal = __ballot(tv[s] > SCORE_THR);
        if (l == s) vword = bal;
    }

    int cnt2 = 0;
#pragma unroll
    for (int s = 0; s < 16; ++s) {
        int flag = rowflag[base + (s << 6) + l];
        uint64_t mm = __ballot(flag != 0);
        if (flag) {
            int pos = cnt2 + __popcll(mm & ((1ULL << l) - 1ULL));
            list[pos] = (s << 6) + l;
        }
        cnt2 += __popcll(mm);
    }

    uint64_t remv = 0;
    for (int chunk = 0; chunk < cnt2; chunk += 64) {
        int mcnt = min(64, cnt2 - chunk);
        int idx_l = chunk + l;
        int myi = list[(idx_l < cnt2) ? idx_l : 0];
        // stage 64 rows x 16 words into LDS (independent loads, one wait)
#pragma unroll
        for (int q = 0; q < 16; ++q) {
            int rr = q * 4 + gg;           // row-in-chunk this lane stages
            int it = chunk + rr;
            if (it < cnt2)
                lrows[rr * 16 + w] = M[(((size_t)(base + list[it])) << 4) + w];
        }
        for (int rr = 0; rr < mcnt; ++rr) {
            int i = __shfl(myi, rr, 64);
            uint64_t row = lrows[rr * 16 + w];          // LDS, addr indep of remv
            uint64_t rb = __shfl(remv, i >> 6, 64);
            bool kept = !((rb >> (i & 63)) & 1ULL);
            remv |= (kept && l < 16) ? row : 0ULL;
        }
    }

    uint64_t kf = vword & ~remv;
#pragma unroll
    for (int s = 0; s < 16; ++s) {
        uint64_t kw = __shfl(kf, s, 64);
        bool kp = (kw >> l) & 1ULL;
        int k = (s << 6) + l;
        float x1 = bx1[base + k], y1 = by1[base + k];
        float x2 = bx2[base + k], y2 = by2[base + k];
        float* po = out + ((size_t)(base + k)) * 6;
        po[0] = kp ? x1 : 0.0f;
        po[1] = kp ? y1 : 0.0f;
        po[2] = kp ? x2 : 0.0f;
        po[3] = kp ? y2 : 0.0f;
        po[4] = kp ? tv[s] : 0.0f;
        po[5] = kp ? (float)tcid[base + k] : 0.0f;
        out[(size_t)NB * TOPK * 6 + base + k] = kp ? 1.0f : 0.0f;
    }
}

extern "C" void kernel_launch(void* const* d_in, const int* in_sizes, int n_in,
                              void* d_out, int out_size, void* d_ws, size_t ws_size,
                              hipStream_t stream) {
    const float* x = (const float*)d_in[0];
    float* out = (float*)d_out;
    char* ws = (char*)d_ws;

    size_t off = 0;
    auto alloc = [&](size_t bytes) { void* p = ws + off; off = (off + bytes + 255) & ~(size_t)255; return p; };
    float*    sval    = (float*)alloc((size_t)NB * NA * 4);
    int*      cid     = (int*)alloc((size_t)NB * NA * 4);
    // hist + cnt + done contiguous -> one memset
    unsigned* hist    = (unsigned*)alloc((size_t)NB * NBIN * 4);     // 512 KB
    unsigned* cnt     = (unsigned*)alloc((size_t)NB * 64 * 4);       // 4 KB (256B stride/batch)
    unsigned* done    = (unsigned*)alloc(256);                       // 16 used
    uint64_t* cand    = (uint64_t*)alloc((size_t)NB * CANDCAP * 8);
    float*    tval    = (float*)alloc((size_t)NB * TOPK * 4);
    float*    bx1     = (float*)alloc((size_t)NB * TOPK * 4);
    float*    by1     = (float*)alloc((size_t)NB * TOPK * 4);
    float*    bx2     = (float*)alloc((size_t)NB * TOPK * 4);
    float*    by2     = (float*)alloc((size_t)NB * TOPK * 4);
    float*    barr    = (float*)alloc((size_t)NB * TOPK * 4);
    int*      tcid    = (int*)alloc((size_t)NB * TOPK * 4);
    int*      rowflag = (int*)alloc((size_t)NB * TOPK * 4);
    uint64_t* M       = (uint64_t*)alloc((size_t)NB * TOPK * 16 * 8);

    size_t zbytes = (size_t)NB * NBIN * 4 + (size_t)NB * 64 * 4 + 256;
    hipMemsetAsync(hist, 0, zbytes, stream);

    score_hist_kernel<<<dim3(33, NB), 256, 0, stream>>>(x, sval, cid, hist);
    select_kernel<<<dim3(16, NB), 256, 0, stream>>>(sval, hist, cand, cnt);
    rank_gather_kernel<<<dim3(4, NB), 256, 0, stream>>>(x, cid, cand, cnt, tval,
                                                        bx1, by1, bx2, by2, barr, tcid);
    mask_sweep_kernel<<<dim3(64, NB), 256, 0, stream>>>(tval, tcid, bx1, by1, bx2, by2,
                                                        barr, M, rowflag, done, out);
}

// Round 8
// 436.281 us; speedup vs baseline: 1.0013x; 1.0013x over previous
//
#include <hip/hip_runtime.h>
#include <cstdint>
#include <cstddef>

#define NB 16
#define NC 84
#define NA 33600
#define NCLS 80
#define TOPK 1024
#define NBIN 8192        // coarse bins: mono_u32 >> 19
#define CANDCAP 8192
#define SCORE_THR 0.005f
#define IOU_THR 0.5f

// ---- 64-bit sort key: (monotonic fp32) << 32 | ~index ----------------------
// Larger key == (higher score, then lower index) == jax.lax.top_k order.
__device__ __forceinline__ unsigned mono_u32(float f) {
    unsigned u = __float_as_uint(f);
    return (u & 0x80000000u) ? ~u : (u | 0x80000000u);
}
__device__ __forceinline__ float key_val(uint64_t k) {
    unsigned u = (unsigned)(k >> 32);
    u = (u & 0x80000000u) ? (u & 0x7FFFFFFFu) : ~u;
    return __uint_as_float(u);
}
__device__ __forceinline__ int key_idx(uint64_t k) {
    return (int)(~(uint32_t)(k & 0xFFFFFFFFu));
}

// ---- K1: max/argmax over 80 classes (float4) + LDS-private histogram -------
// grid (33, NB): block handles 1024 anchors (256 float4) of one batch.
__global__ __launch_bounds__(256) void score_hist_kernel(const float* __restrict__ x,
                                                         float* __restrict__ sval,
                                                         int* __restrict__ cid,
                                                         unsigned* __restrict__ hist) {
    __shared__ unsigned h[NBIN];
    const int t = threadIdx.x;
    const int b = blockIdx.y;
    for (int i = t; i < NBIN; i += 256) h[i] = 0;
    __syncthreads();
    int q = blockIdx.x * 256 + t;                 // float4 index within batch
    if (q < NA / 4) {
        const float4* p = (const float4*)(x + (size_t)b * NC * NA + (size_t)4 * NA) + q;
        float4 best = p[0];
        int4 bc = {0, 0, 0, 0};
#pragma unroll 8
        for (int c = 1; c < NCLS; ++c) {
            float4 v = p[(size_t)c * (NA / 4)];
            if (v.x > best.x) { best.x = v.x; bc.x = c; }
            if (v.y > best.y) { best.y = v.y; bc.y = c; }
            if (v.z > best.z) { best.z = v.z; bc.z = c; }
            if (v.w > best.w) { best.w = v.w; bc.w = c; }
        }
        float4 s;
        s.x = (best.x > SCORE_THR) ? best.x : -INFINITY;
        s.y = (best.y > SCORE_THR) ? best.y : -INFINITY;
        s.z = (best.z > SCORE_THR) ? best.z : -INFINITY;
        s.w = (best.w > SCORE_THR) ? best.w : -INFINITY;
        ((float4*)sval)[(size_t)b * (NA / 4) + q] = s;
        ((int4*)cid)[(size_t)b * (NA / 4) + q] = bc;
        atomicAdd(&h[mono_u32(s.x) >> 19], 1u);
        atomicAdd(&h[mono_u32(s.y) >> 19], 1u);
        atomicAdd(&h[mono_u32(s.z) >> 19], 1u);
        atomicAdd(&h[mono_u32(s.w) >> 19], 1u);
    }
    __syncthreads();
    unsigned* gh = hist + (size_t)b * NBIN;
    for (int i = t; i < NBIN; i += 256) {
        unsigned v = h[i];
        if (v) atomicAdd(&gh[i], v);
    }
}

// ---- K2: per-block cutbin recompute + compact slice ------------------------
// grid (16, NB): each block scans the (L2-hot) hist, then compacts 2100 anchors.
__global__ __launch_bounds__(256) void select_kernel(const float* __restrict__ sval,
                                                     const unsigned* __restrict__ hist,
                                                     uint64_t* __restrict__ cand,
                                                     unsigned* __restrict__ cnt) {
    __shared__ unsigned csum[256];
    __shared__ unsigned scut, lc, lbase;
    __shared__ uint64_t cbuf[2112];
    const int t = threadIdx.x;
    const int b = blockIdx.y;
    const int sl = blockIdx.x;

    const unsigned* gh = hist + (size_t)b * NBIN;
    unsigned cnts[32];
    unsigned local = 0;
#pragma unroll
    for (int q = 0; q < 32; ++q) {
        cnts[q] = gh[NBIN - 1 - (t * 32 + q)];
        local += cnts[q];
    }
    csum[t] = local;
    __syncthreads();
    for (int off = 1; off < 256; off <<= 1) {
        unsigned v = (t >= off) ? csum[t - off] : 0u;
        __syncthreads();
        csum[t] += v;
        __syncthreads();
    }
    unsigned incl = csum[t], excl = incl - local;
    if (excl < TOPK && incl >= TOPK) {
        unsigned cum = excl;
#pragma unroll
        for (int q = 0; q < 32; ++q) {
            if (cum + cnts[q] >= TOPK) { scut = (unsigned)(NBIN - 1 - (t * 32 + q)); break; }
            cum += cnts[q];
        }
    }
    if (t == 0) lc = 0;
    __syncthreads();
    unsigned cb = scut;

    int a0 = sl * (NA / 16);
    const float* sv = sval + (size_t)b * NA;
    for (int a = a0 + t; a < a0 + NA / 16; a += 256) {
        unsigned u = mono_u32(sv[a]);
        if ((u >> 19) >= cb) {
            unsigned pos = atomicAdd(&lc, 1u);
            cbuf[pos] = ((uint64_t)u << 32) | (uint32_t)(~(uint32_t)a);
        }
    }
    __syncthreads();
    if (t == 0) lbase = lc ? atomicAdd(&cnt[b * 64], lc) : 0u;
    __syncthreads();
    for (unsigned i = t; i < lc; i += 256) {
        unsigned p = lbase + i;
        if (p < CANDCAP) cand[((size_t)b << 13) + p] = cbuf[i];
    }
}

// ---- K3: exact top-1024 by rank-counting + fused box/cid gather ------------
// grid (4, NB). Keys unique -> ranks unique -> output bit-identical to top_k.
__global__ __launch_bounds__(256) void rank_gather_kernel(const float* __restrict__ x,
                                                          const int* __restrict__ cid,
                                                          const uint64_t* __restrict__ cand,
                                                          const unsigned* __restrict__ cnt,
                                                          float* __restrict__ tval,
                                                          float* __restrict__ bx1, float* __restrict__ by1,
                                                          float* __restrict__ bx2, float* __restrict__ by2,
                                                          float* __restrict__ barr, int* __restrict__ tcid) {
    __shared__ uint64_t lk[CANDCAP];   // 64 KB
    const int t = threadIdx.x;
    const int b = blockIdx.y;
    const int sl = blockIdx.x;
    unsigned C = cnt[b * 64];
    if (C > CANDCAP) C = CANDCAP;
    const uint64_t* cb = cand + ((size_t)b << 13);
    for (unsigned i = t; i < C; i += 256) lk[i] = cb[i];
    __syncthreads();

    const int base = b << 10;
    const float* xb = x + (size_t)b * NC * NA;
    for (int i0 = sl * 256 + t; i0 < (int)C; i0 += 1024) {
        uint64_t my = lk[i0];
        unsigned rank = 0;
        int j = 0;
        for (; j + 4 <= (int)C; j += 4) {
            rank += (lk[j] > my);
            rank += (lk[j + 1] > my);
            rank += (lk[j + 2] > my);
            rank += (lk[j + 3] > my);
        }
        for (; j < (int)C; ++j) rank += (lk[j] > my);
        if (rank < TOPK) {
            int idx = key_idx(my);
            tval[base + rank] = key_val(my);
            float x1 = xb[idx], y1 = xb[NA + idx], x2 = xb[2 * NA + idx], y2 = xb[3 * NA + idx];
            bx1[base + rank] = x1; by1[base + rank] = y1;
            bx2[base + rank] = x2; by2[base + rank] = y2;
            barr[base + rank] = (x2 - x1) * (y2 - y1);
            tcid[base + rank] = cid[b * NA + idx];
        }
    }
}

// ---- K4: suppression bit-matrix + last-block-fused serial sweep ------------
// grid (64, NB): block handles 16 rows. Last finishing block of each batch
// (device-scope done counter, 256B-padded, fence/acquire) runs the sweep.
// Sweep chain avoids cross-lane shfl of live state: kept-test is a __ballot
// (one v_cmp -> SGPR); row index comes from wave-uniform LDS list[]; row bits
// and next index are software-pipelined one iteration ahead.
#define LDSPAD(j) ((j) + ((j) >> 6))
__global__ __launch_bounds__(256) void mask_sweep_kernel(const float* __restrict__ tval,
                                                         const int* __restrict__ tcid,
                                                         const float* __restrict__ bx1,
                                                         const float* __restrict__ by1,
                                                         const float* __restrict__ bx2,
                                                         const float* __restrict__ by2,
                                                         const float* __restrict__ barr,
                                                         uint64_t* __restrict__ M,
                                                         int* __restrict__ rowflag,
                                                         unsigned* __restrict__ done,
                                                         float* __restrict__ out) {
    // smem layout: [0,20800) box SoA (5 x 1040 floats)  — reused as lrows in sweep
    //              [20800,21824) anyf                   [21824,25920) list
    __shared__ __align__(16) char smem[25920];
    __shared__ unsigned sdone;
    float* sx1 = (float*)smem;
    float* sy1 = sx1 + (TOPK + 16);
    float* sx2 = sy1 + (TOPK + 16);
    float* sy2 = sx2 + (TOPK + 16);
    float* sar = sy2 + (TOPK + 16);
    int* anyf = (int*)(smem + 20800);
    int* list = (int*)(smem + 21824);

    const int t = threadIdx.x;
    const int b = blockIdx.y;
    const int base = b << 10;

    for (int j = t; j < TOPK; j += 256) {
        int ji = LDSPAD(j);
        sx1[ji] = bx1[base + j]; sy1[ji] = by1[base + j];
        sx2[ji] = bx2[base + j]; sy2[ji] = by2[base + j];
        sar[ji] = barr[base + j];
    }
    __syncthreads();

    int w = t & 15;
    int r = (blockIdx.x << 4) + (t >> 4);
    int ri = LDSPAD(r);
    float ix1 = sx1[ri], iy1 = sy1[ri], ix2 = sx2[ri], iy2 = sy2[ri], ia = sar[ri];
    uint64_t m = 0;
#pragma unroll 8
    for (int jj = 0; jj < 64; ++jj) {
        int j = (w << 6) + jj;
        int ji = w * 65 + jj;
        float ltx = fmaxf(ix1, sx1[ji]);
        float lty = fmaxf(iy1, sy1[ji]);
        float rbx = fminf(ix2, sx2[ji]);
        float rby = fminf(iy2, sy2[ji]);
        float ww = fmaxf(rbx - ltx, 0.0f);
        float hh = fmaxf(rby - lty, 0.0f);
        float inter = ww * hh;
        float uni = ia + sar[ji] - inter;      // same op order as reference
        float iou = inter / fmaxf(uni, 1e-9f);
        if (j > r && iou > IOU_THR) m |= (1ULL << jj);
    }
    M[(((size_t)(base + r)) << 4) + w] = m;
    anyf[t] = (m != 0ULL);
    __syncthreads();
    if (w == 0) {
        int any = 0;
#pragma unroll
        for (int q = 0; q < 16; ++q) any |= anyf[t + q];
        bool valid = tval[base + r] > SCORE_THR;
        rowflag[base + r] = (any && valid) ? 1 : 0;
    }

    // ---- publish, then elect last block (done padded: 1 counter / 256 B) ----
    __syncthreads();
    __threadfence();
    if (t == 0)
        sdone = __hip_atomic_fetch_add(&done[b * 64], 1u, __ATOMIC_ACQ_REL, __HIP_MEMORY_SCOPE_AGENT);
    __syncthreads();
    if (sdone != 63) return;

    // ---- serial greedy sweep (wave 0 only; no __syncthreads below) ----
    if (t >= 64) return;
    int l = t;
    int gg = l >> 4;
    w = l & 15;
    uint64_t* lrows = (uint64_t*)smem;   // overlays dead box SoA; 64*16*8 = 8 KB

    float tv[16];
#pragma unroll
    for (int s = 0; s < 16; ++s) tv[s] = tval[base + (s << 6) + l];

    uint64_t vword = 0;
#pragma unroll
    for (int s = 0; s < 16; ++s) {
        uint64_t bal = __ballot(tv[s] > SCORE_THR);
        if (l == s) vword = bal;
    }

    int cnt2 = 0;
#pragma unroll
    for (int s = 0; s < 16; ++s) {
        int flag = rowflag[base + (s << 6) + l];
        uint64_t mm = __ballot(flag != 0);
        if (flag) {
            int pos = cnt2 + __popcll(mm & ((1ULL << l) - 1ULL));
            list[pos] = (s << 6) + l;
        }
        cnt2 += __popcll(mm);
    }

    uint64_t remv = 0;   // word w authoritative in lane w (<16); 0 elsewhere
    for (int chunk = 0; chunk < cnt2; chunk += 64) {
        int mcnt = min(64, cnt2 - chunk);
        // stage 64 rows x 16 words into LDS (independent loads, one wait)
#pragma unroll
        for (int q = 0; q < 16; ++q) {
            int rr = q * 4 + gg;           // row-in-chunk this lane stages
            int it = chunk + rr;
            if (it < cnt2)
                lrows[rr * 16 + w] = M[(((size_t)(base + list[it])) << 4) + w];
        }
        int i_cur = list[chunk];
        uint64_t row_cur = lrows[w];
        for (int rr = 0; rr < mcnt; ++rr) {
            int i_nxt = 0; uint64_t row_nxt = 0;
            if (rr + 1 < mcnt) {           // prefetch: indep of remv chain
                i_nxt = list[chunk + rr + 1];
                row_nxt = lrows[(rr + 1) * 16 + w];
            }
            // kept-test via ballot: only lane i>>6 contributes its bit
            bool rem_i = (l == (i_cur >> 6)) && ((remv >> (i_cur & 63)) & 1ULL);
            bool kept = (__ballot(rem_i) == 0ULL);
            remv |= (kept && l < 16) ? row_cur : 0ULL;
            i_cur = i_nxt; row_cur = row_nxt;
        }
    }

    uint64_t kf = vword & ~remv;
#pragma unroll
    for (int s = 0; s < 16; ++s) {
        uint64_t kw = __shfl(kf, s, 64);
        bool kp = (kw >> l) & 1ULL;
        int k = (s << 6) + l;
        float x1 = bx1[base + k], y1 = by1[base + k];
        float x2 = bx2[base + k], y2 = by2[base + k];
        float* po = out + ((size_t)(base + k)) * 6;
        po[0] = kp ? x1 : 0.0f;
        po[1] = kp ? y1 : 0.0f;
        po[2] = kp ? x2 : 0.0f;
        po[3] = kp ? y2 : 0.0f;
        po[4] = kp ? tv[s] : 0.0f;
        po[5] = kp ? (float)tcid[base + k] : 0.0f;
        out[(size_t)NB * TOPK * 6 + base + k] = kp ? 1.0f : 0.0f;
    }
}

extern "C" void kernel_launch(void* const* d_in, const int* in_sizes, int n_in,
                              void* d_out, int out_size, void* d_ws, size_t ws_size,
                              hipStream_t stream) {
    const float* x = (const float*)d_in[0];
    float* out = (float*)d_out;
    char* ws = (char*)d_ws;

    size_t off = 0;
    auto alloc = [&](size_t bytes) { void* p = ws + off; off = (off + bytes + 255) & ~(size_t)255; return p; };
    float*    sval    = (float*)alloc((size_t)NB * NA * 4);
    int*      cid     = (int*)alloc((size_t)NB * NA * 4);
    // hist + cnt + done contiguous -> one memset
    unsigned* hist    = (unsigned*)alloc((size_t)NB * NBIN * 4);     // 512 KB
    unsigned* cnt     = (unsigned*)alloc((size_t)NB * 64 * 4);       // 4 KB (256B stride/batch)
    unsigned* done    = (unsigned*)alloc((size_t)NB * 64 * 4);       // 4 KB (256B stride/batch)
    uint64_t* cand    = (uint64_t*)alloc((size_t)NB * CANDCAP * 8);
    float*    tval    = (float*)alloc((size_t)NB * TOPK * 4);
    float*    bx1     = (float*)alloc((size_t)NB * TOPK * 4);
    float*    by1     = (float*)alloc((size_t)NB * TOPK * 4);
    float*    bx2     = (float*)alloc((size_t)NB * TOPK * 4);
    float*    by2     = (float*)alloc((size_t)NB * TOPK * 4);
    float*    barr    = (float*)alloc((size_t)NB * TOPK * 4);
    int*      tcid    = (int*)alloc((size_t)NB * TOPK * 4);
    int*      rowflag = (int*)alloc((size_t)NB * TOPK * 4);
    uint64_t* M       = (uint64_t*)alloc((size_t)NB * TOPK * 16 * 8);

    size_t zbytes = (size_t)NB * NBIN * 4 + (size_t)NB * 64 * 4 * 2;
    hipMemsetAsync(hist, 0, zbytes, stream);

    score_hist_kernel<<<dim3(33, NB), 256, 0, stream>>>(x, sval, cid, hist);
    select_kernel<<<dim3(16, NB), 256, 0, stream>>>(sval, hist, cand, cnt);
    rank_gather_kernel<<<dim3(4, NB), 256, 0, stream>>>(x, cid, cand, cnt, tval,
                                                        bx1, by1, bx2, by2, barr, tcid);
    mask_sweep_kernel<<<dim3(64, NB), 256, 0, stream>>>(tval, tcid, bx1, by1, bx2, by2,
                                                        barr, M, rowflag, done, out);
}